// Round 8
// baseline (226.181 us; speedup 1.0000x reference)
//
#include <hip/hip_runtime.h>
#include <hip/hip_bf16.h>

#define Dd 2048
#define Ss 2048
#define Bb 2
#define Hh 16
#define HDd 128
#define BSs (Bb*Ss)
#define NTIL 32  // 2048 / 64 K-tiles

typedef __bf16 bf16;
typedef __bf16 bf16x8 __attribute__((ext_vector_type(8)));
typedef __bf16 bf16x4 __attribute__((ext_vector_type(4)));
typedef float f32x4 __attribute__((ext_vector_type(4)));

__device__ __forceinline__ void gload_lds16(const void* g, void* l) {
  __builtin_amdgcn_global_load_lds((__attribute__((address_space(1))) void*)(g),
                                   (__attribute__((address_space(3))) void*)(l), 16, 0, 0);
}

template <int N>
__device__ __forceinline__ void waitv() {
  if constexpr (N == 0) asm volatile("s_waitcnt vmcnt(0)" ::: "memory");
  else if constexpr (N == 6) asm volatile("s_waitcnt vmcnt(6)" ::: "memory");
  // N < 0: no wait
}

// ---------------- x -> bf16 ----------------
__global__ void k_cvtx(const float* __restrict__ x, bf16* __restrict__ xb) {
  int i = (blockIdx.x * 256 + threadIdx.x) * 4;
  f32x4 v = *(const f32x4*)(x + i);
  bf16x4 o;
  o[0] = (bf16)v[0]; o[1] = (bf16)v[1]; o[2] = (bf16)v[2]; o[3] = (bf16)v[3];
  *(bf16x4*)(xb + i) = o;
}

// ------------- W [K][N] fp32 -> Wt [N][K] bf16 (x4 weights), 64x64 tiles, vectorized -------------
__global__ void k_tw(const float* __restrict__ W0, const float* __restrict__ W1,
                     const float* __restrict__ W2, const float* __restrict__ W3,
                     bf16* __restrict__ T0, bf16* __restrict__ T1,
                     bf16* __restrict__ T2, bf16* __restrict__ T3) {
  const float* W; bf16* T;
  switch (blockIdx.z) {
    case 0: W = W0; T = T0; break;
    case 1: W = W1; T = T1; break;
    case 2: W = W2; T = T2; break;
    default: W = W3; T = T3; break;
  }
  __shared__ float t[64][65];
  int n0 = blockIdx.x * 64, k0 = blockIdx.y * 64;
  int tid = threadIdx.x;  // 256
#pragma unroll
  for (int rr = 0; rr < 4; rr++) {
    int r = (tid >> 4) + rr * 16;
    f32x4 vv = *(const f32x4*)(W + (size_t)(k0 + r) * Dd + n0 + (tid & 15) * 4);
#pragma unroll
    for (int j = 0; j < 4; j++) t[r][(tid & 15) * 4 + j] = vv[j];
  }
  __syncthreads();
#pragma unroll
  for (int rr = 0; rr < 4; rr++) {
    int n = rr * 16 + (tid >> 4);
    int kb = (tid & 15) * 4;
    bf16x4 o;
#pragma unroll
    for (int j = 0; j < 4; j++) o[j] = (bf16)t[kb + j][n];
    *(bf16x4*)(T + (size_t)(n0 + n) * Dd + k0 + kb) = o;
  }
}

// ------------- doc position ids (prefix-max scan per batch) -------------
__global__ void k_pos(const int* __restrict__ doc, int* __restrict__ pos) {
  int b = blockIdx.x;
  __shared__ int bp[2][Ss];
  const int* db = doc + (size_t)b * Ss;
  for (int i = threadIdx.x; i < Ss; i += 1024) {
    int bd = (i == 0) || (db[i] != db[i - 1]);
    bp[0][i] = bd ? i : 0;
  }
  __syncthreads();
  int src = 0;
  for (int off = 1; off < Ss; off <<= 1) {
    for (int i = threadIdx.x; i < Ss; i += 1024) {
      int v = bp[src][i];
      if (i >= off) v = max(v, bp[src][i - off]);
      bp[1 - src][i] = v;
    }
    __syncthreads();
    src = 1 - src;
  }
  for (int i = threadIdx.x; i < Ss; i += 1024)
    pos[(size_t)b * Ss + i] = i - bp[src][i];
}

// ================= 128x256 BK=64 GEMM core, TRIPLE-buffered, 1 barrier/K-tile =================
// Round-6 proven core (108.9 us, MfmaUtil 40, conflicts 262K). Unchanged.
__device__ __forceinline__ void stage64(const char* gA, const char* gB,
                                        int m0, int n0, int t, int buf,
                                        char* AL, char* BL, int tid) {
  int ktb = t * 128;  // K-tile byte offset in a 4096 B row
#pragma unroll
  for (int p = 0; p < 2; p++) {
    int o = p * 8192 + tid * 16;
    int r = o >> 7, cb = o & 127;
    gload_lds16(gA + (size_t)(m0 + r) * 4096 + ktb + (cb ^ ((r & 7) << 4)),
                AL + buf * 16384 + o);
  }
#pragma unroll
  for (int p = 0; p < 4; p++) {
    int o = p * 8192 + tid * 16;
    int r = o >> 7, cb = o & 127;
    gload_lds16(gB + (size_t)(n0 + r) * 4096 + ktb + (cb ^ ((r & 7) << 4)),
                BL + buf * 32768 + o);
  }
}

template <bool STAGE, int WV>
__device__ __forceinline__ void do_tile64(const char* gA, const char* gB, int m0, int n0,
                                          int t, int bi, int b2, char* AL, char* BL, int tid,
                                          int wr, int wc, int ln, int g,
                                          f32x4 (&acc)[4][4]) {
  if (STAGE) stage64(gA, gB, m0, n0, t + 2, b2, AL, BL, tid);
  const char* tA = AL + bi * 16384;
  const char* tB = BL + bi * 32768;
#pragma unroll
  for (int kk = 0; kk < 2; kk++) {
    bf16x8 af[4], bf[4];
#pragma unroll
    for (int mq = 0; mq < 4; mq++) {
      int row = wr * 64 + mq * 16 + ln;
      af[mq] = *(const bf16x8*)(tA + row * 128 + ((kk * 64 + g * 16) ^ ((row & 7) << 4)));
    }
#pragma unroll
    for (int nq = 0; nq < 4; nq++) {
      int row = wc * 64 + nq * 16 + ln;
      bf[nq] = *(const bf16x8*)(tB + row * 128 + ((kk * 64 + g * 16) ^ ((row & 7) << 4)));
    }
    __builtin_amdgcn_s_setprio(1);
#pragma unroll
    for (int mq = 0; mq < 4; mq++)
#pragma unroll
      for (int nq = 0; nq < 4; nq++)
        acc[mq][nq] = __builtin_amdgcn_mfma_f32_16x16x32_bf16(af[mq], bf[nq], acc[mq][nq], 0, 0, 0);
    __builtin_amdgcn_s_setprio(0);
  }
  waitv<WV>();
  __builtin_amdgcn_s_barrier();
}

__device__ __forceinline__ void gemm64_core(const bf16* gA_, const bf16* gB_,
                                            int m0, int n0, char* AL, char* BL,
                                            f32x4 (&acc)[4][4]) {
  const char* gA = (const char*)gA_;
  const char* gB = (const char*)gB_;
  const int tid = threadIdx.x;
  const int l = tid & 63, w = tid >> 6;
  const int wr = w >> 2, wc = w & 3;
  const int g = l >> 4, ln = l & 15;
  f32x4 z = {0.f, 0.f, 0.f, 0.f};
#pragma unroll
  for (int i = 0; i < 4; i++)
#pragma unroll
    for (int n = 0; n < 4; n++) acc[i][n] = z;

  stage64(gA, gB, m0, n0, 0, 0, AL, BL, tid);
  stage64(gA, gB, m0, n0, 1, 1, AL, BL, tid);
  waitv<6>();
  __builtin_amdgcn_s_barrier();

  for (int tt = 0; tt < 10; tt++) {
    int t = tt * 3;
    do_tile64<true, 6>(gA, gB, m0, n0, t,     0, 2, AL, BL, tid, wr, wc, ln, g, acc);
    do_tile64<true, 6>(gA, gB, m0, n0, t + 1, 1, 0, AL, BL, tid, wr, wc, ln, g, acc);
    do_tile64<true, 6>(gA, gB, m0, n0, t + 2, 2, 1, AL, BL, tid, wr, wc, ln, g, acc);
  }
  do_tile64<false, 0>(gA, gB, m0, n0, 30, 0, 0, AL, BL, tid, wr, wc, ln, g, acc);
  do_tile64<false, -1>(gA, gB, m0, n0, 31, 1, 0, AL, BL, tid, wr, wc, ln, g, acc);
}

// ------------- fused QKV projection + RoPE epilogue (128x256 tiles, 768 blocks = 3 exact rounds) -------------
// XCD-partitioned swizzle: XCD x owns nt in {3x,3x+1,3x+2} (B-panels 1.6 MB, L2-resident)
// for ALL 32 mt, mt-major. Round-6 proven (FETCH 107 MB). Unchanged.
__global__ __launch_bounds__(512, 2) void k_qkv256(const bf16* __restrict__ xb,
                                                   const bf16* __restrict__ wqkvt,
                                                   const int* __restrict__ pos,
                                                   bf16* __restrict__ q,
                                                   bf16* __restrict__ k,
                                                   bf16* __restrict__ vt) {
  __shared__ char SLM[147456];  // GEMM: A 3x16K + B 3x32K; epilogue: 64x260 f32 view (65 KB)
  char* AL = SLM;
  char* BL = SLM + 49152;
  int bid = blockIdx.x;                    // 768 blocks
  int x = bid & 7, j = bid >> 3;           // x = XCD, j = 0..95
  int mt = j / 3, nt = x * 3 + (j % 3);    // per-XCD: 3 nt panels x all mt, mt-major
  int m0 = mt * 128, n0 = nt * 256;

  f32x4 acc[4][4];
  gemm64_core(xb, wqkvt, m0, n0, AL, BL, acc);

  const int tid = threadIdx.x;
  const int l = tid & 63, w = tid >> 6;
  const int wr = w >> 2, wc = w & 3, g = l >> 4, ln = l & 15;
  int z = n0 >> 11;                         // 0=Q 1=K 2=V (block-uniform)
  int n0l = n0 & 2047;
  int bix = m0 >> 11;
  int sl0 = m0 & 2047;                      // 128-row tile never crosses batch boundary

  if (z == 2) {
    // V: straight from acc, transposed layout [B][H][HD][S], 8 B stores
#pragma unroll
    for (int mq = 0; mq < 4; mq++) {
      int sl = sl0 + wr * 64 + mq * 16 + g * 4;
#pragma unroll
      for (int nq = 0; nq < 4; nq++) {
        int col = n0l + wc * 64 + nq * 16 + ln;
        int h = col >> 7, hd = col & 127;
        bf16x4 o;
#pragma unroll
        for (int r2 = 0; r2 < 4; r2++) o[r2] = (bf16)acc[mq][nq][r2];
        *(bf16x4*)(vt + (((size_t)(bix * Hh + h) * HDd + hd) * Ss + sl)) = o;
      }
    }
  } else {
    bf16* dst = (z == 0) ? q : k;
    float* T = (float*)SLM;                 // stride 260 floats, 64 rows per pass
    const float c1 = 0.14391156642398168f;  // ln(10000)/64
    int cg = (tid & 31) * 8;                // per-thread column base (8 consecutive cols)
    int hb = n0l + cg;
    int hh = hb >> 7, hd0 = hb & 127;       // constant per thread
    float fr[4];
#pragma unroll
    for (int pr = 0; pr < 4; pr++)
      fr[pr] = __expf(-(float)((hd0 >> 1) + pr) * c1);

#pragma unroll
    for (int pass = 0; pass < 2; pass++) {
      __syncthreads();
      // scatter 64 rows of acc into LDS (waves with wr==pass own these rows)
      if (wr == pass) {
#pragma unroll
        for (int mq = 0; mq < 4; mq++) {
#pragma unroll
          for (int nq = 0; nq < 4; nq++) {
            int c = wc * 64 + nq * 16 + ln;
            int rb = mq * 16 + g * 4;
#pragma unroll
            for (int r2 = 0; r2 < 4; r2++)
              T[(rb + r2) * 260 + c] = acc[mq][nq][r2];
          }
        }
      }
      __syncthreads();
      // gather rows: 8 consecutive hd per thread, RoPE pairs in-register, 16 B stores
#pragma unroll
      for (int j2 = 0; j2 < 4; j2++) {
        int r = j2 * 16 + (tid >> 5);
        int sg = m0 + pass * 64 + r;
        float p = (float)pos[sg];
        f32x4 v0 = *(const f32x4*)(T + r * 260 + cg);
        f32x4 v1 = *(const f32x4*)(T + r * 260 + cg + 4);
        float e0[4] = {v0[0], v0[2], v1[0], v1[2]};
        float e1[4] = {v0[1], v0[3], v1[1], v1[3]};
        int s = sg & 2047;
        bf16x8 o;
#pragma unroll
        for (int pr = 0; pr < 4; pr++) {
          float ang = p * fr[pr];
          float sn, cs;
          __sincosf(ang, &sn, &cs);
          o[2 * pr]     = (bf16)(e0[pr] * cs - e1[pr] * sn);
          o[2 * pr + 1] = (bf16)(e1[pr] * cs + e0[pr] * sn);
        }
        *(bf16x8*)(dst + (((size_t)(bix * Hh + hh) * Ss + s) * HDd + hd0)) = o;
      }
    }
  }
}

// ------------- final projection + bias (fp32 out), 128x256 tiles, 256 blocks = 1 exact round -------------
// XCD-partitioned: XCD x owns nt = x (one 0.5 MB wot panel, L2-resident) x all 32 mt.
__global__ __launch_bounds__(512, 2) void k_out256(const bf16* __restrict__ ctx,
                                                   const bf16* __restrict__ wot,
                                                   const float* __restrict__ bo,
                                                   float* __restrict__ outp) {
  __shared__ char AL[49152];
  __shared__ char BL[98304];
  int bid = blockIdx.x;                    // 256 blocks
  int x = bid & 7, j = bid >> 3;           // x = XCD, j = 0..31
  int mt = j, nt = x;
  int m0 = mt * 128, n0 = nt * 256;

  f32x4 acc[4][4];
  gemm64_core(ctx, wot, m0, n0, AL, BL, acc);

  const int l = threadIdx.x & 63, w = threadIdx.x >> 6;
  const int wr = w >> 2, wc = w & 3, g = l >> 4, ln = l & 15;
  float bov[4];
#pragma unroll
  for (int nq = 0; nq < 4; nq++)
    bov[nq] = bo[n0 + wc * 64 + nq * 16 + ln];
#pragma unroll
  for (int mq = 0; mq < 4; mq++)
#pragma unroll
    for (int r2 = 0; r2 < 4; r2++) {
      int row = m0 + wr * 64 + mq * 16 + g * 4 + r2;
#pragma unroll
      for (int nq = 0; nq < 4; nq++) {
        int col = n0 + wc * 64 + nq * 16 + ln;
        outp[(size_t)row * Dd + col] = acc[mq][nq][r2] + bov[nq];
      }
    }
}

// ------------- flash attention with doc+causal mask -------------
// THIS ROUND: 128-row Q-blocks, 8 waves (512 thr). Halves total kv-iterations
// (~272 vs ~528 per bh) -> halves K/V staging traffic, barriers, and mask/softmax
// VALU per MFMA. Per-wave math identical to the round-6 4-wave version.
// LDS 48 KB (Ks 16 + Vts 16 + Pw 8x2). Grid 512, XCD x owns 4 heads.
__global__ __launch_bounds__(512) void k_attn(const bf16* __restrict__ q,
                                              const bf16* __restrict__ k,
                                              const bf16* __restrict__ vt,
                                              const int* __restrict__ pos,
                                              bf16* __restrict__ ctx) {
  __shared__ bf16 Ks[64 * 128];    // K tile  [kv][hd]
  __shared__ bf16 Vts[128 * 64];   // Vt tile [hd][kv]
  __shared__ bf16 Pw[8][16 * 64];  // per-wave P [qrow][kv]
  int bid = blockIdx.x;            // 512
  int xc = bid & 7, jj = bid >> 3; // jj = 0..63
  int bh = xc * 4 + (jj >> 4);     // 4 heads per XCD (K/V L2-resident)
  int qt = jj & 15;
  int b = bh >> 4, h = bh & 15;
  int q0 = qt * 128;
  const int tid = threadIdx.x, l = tid & 63, w = tid >> 6, g = l >> 4, ln = l & 15;
  const bf16* qb = q + (size_t)bh * Ss * HDd;
  const bf16* kb = k + (size_t)bh * Ss * HDd;
  const bf16* vb = vt + (size_t)bh * Ss * HDd;

  bf16x8 qf[4];
  int qr = q0 + w * 16 + ln;
#pragma unroll
  for (int ks = 0; ks < 4; ks++)
    qf[ks] = *(const bf16x8*)(qb + (size_t)qr * HDd + ks * 32 + 8 * g);

  int rrow[4], dstart[4];
  float m[4], lsum[4];
#pragma unroll
  for (int r2 = 0; r2 < 4; r2++) {
    rrow[r2] = q0 + w * 16 + 4 * g + r2;
    dstart[r2] = rrow[r2] - pos[(size_t)b * Ss + rrow[r2]];
    m[r2] = -1e30f;
    lsum[r2] = 0.f;
  }
  f32x4 oacc[8];
  f32x4 z = {0.f, 0.f, 0.f, 0.f};
#pragma unroll
  for (int n = 0; n < 8; n++) oacc[n] = z;

  // kt_start from the block's first row is a valid lower bound (doc starts are
  // non-decreasing in s); fully-masked tiles are exact no-ops (alpha=1, rs=0).
  int kt_start = (q0 - pos[(size_t)b * Ss + q0]) >> 6;
  int kt_end = (q0 + 127) >> 6;
  const float iscale = 0.08838834764831845f;  // 1/sqrt(128)

  for (int kt = kt_start; kt <= kt_end; kt++) {
    int kv0 = kt * 64;
#pragma unroll
    for (int i2 = 0; i2 < 2; i2++) {
      int o = i2 * 8192 + w * 1024 + l * 16;
      int rk = o >> 8, cbk = o & 255;
      gload_lds16((const char*)kb + (size_t)(kv0 + rk) * 256 + cbk,
                  (char*)Ks + i2 * 8192 + w * 1024);
      int rv = o >> 7, cbv = o & 127;
      gload_lds16((const char*)vb + (size_t)rv * (Ss * 2) + (size_t)kv0 * 2 + cbv,
                  (char*)Vts + i2 * 8192 + w * 1024);
    }
    __syncthreads();

    f32x4 sc[4];
#pragma unroll
    for (int n = 0; n < 4; n++) {
      f32x4 a = z;
#pragma unroll
      for (int ks = 0; ks < 4; ks++) {
        bf16x8 bfrag = *(const bf16x8*)(Ks + (n * 16 + ln) * 128 + ks * 32 + 8 * g);
        a = __builtin_amdgcn_mfma_f32_16x16x32_bf16(qf[ks], bfrag, a, 0, 0, 0);
      }
      sc[n] = a;
    }

    float pmax[4] = {-1e30f, -1e30f, -1e30f, -1e30f};
    float pv[4][4];
#pragma unroll
    for (int n = 0; n < 4; n++) {
      int kvc = kv0 + n * 16 + ln;
#pragma unroll
      for (int r2 = 0; r2 < 4; r2++) {
        bool ok = (kvc <= rrow[r2]) && (kvc >= dstart[r2]);
        float sv = ok ? sc[n][r2] * iscale : -1e30f;
        pv[n][r2] = sv;
        pmax[r2] = fmaxf(pmax[r2], sv);
      }
    }
#pragma unroll
    for (int off = 1; off < 16; off <<= 1)
#pragma unroll
      for (int r2 = 0; r2 < 4; r2++)
        pmax[r2] = fmaxf(pmax[r2], __shfl_xor(pmax[r2], off, 64));

    float alpha[4];
#pragma unroll
    for (int r2 = 0; r2 < 4; r2++) {
      float mn = fmaxf(m[r2], pmax[r2]);
      alpha[r2] = __expf(m[r2] - mn);
      m[r2] = mn;
    }

    float rs[4] = {0.f, 0.f, 0.f, 0.f};
#pragma unroll
    for (int n = 0; n < 4; n++) {
      int kvc = kv0 + n * 16 + ln;
#pragma unroll
      for (int r2 = 0; r2 < 4; r2++) {
        bool ok = (kvc <= rrow[r2]) && (kvc >= dstart[r2]);
        float p = ok ? __expf(pv[n][r2] - m[r2]) : 0.f;
        rs[r2] += p;
        Pw[w][(4 * g + r2) * 64 + n * 16 + ln] = (bf16)p;
      }
    }
#pragma unroll
    for (int off = 1; off < 16; off <<= 1)
#pragma unroll
      for (int r2 = 0; r2 < 4; r2++) rs[r2] += __shfl_xor(rs[r2], off, 64);
#pragma unroll
    for (int r2 = 0; r2 < 4; r2++) lsum[r2] = lsum[r2] * alpha[r2] + rs[r2];
#pragma unroll
    for (int n = 0; n < 8; n++)
#pragma unroll
      for (int r2 = 0; r2 < 4; r2++) oacc[n][r2] *= alpha[r2];
    __syncthreads();

#pragma unroll
    for (int n = 0; n < 8; n++) {
#pragma unroll
      for (int ks = 0; ks < 2; ks++) {
        bf16x8 pa = *(const bf16x8*)(&Pw[w][ln * 64 + ks * 32 + 8 * g]);
        bf16x8 vfr = *(const bf16x8*)(Vts + (n * 16 + ln) * 64 + ks * 32 + 8 * g);
        oacc[n] = __builtin_amdgcn_mfma_f32_16x16x32_bf16(pa, vfr, oacc[n], 0, 0, 0);
      }
    }
    __syncthreads();
  }

#pragma unroll
  for (int n = 0; n < 8; n++)
#pragma unroll
    for (int r2 = 0; r2 < 4; r2++) {
      float val = oacc[n][r2] / lsum[r2];
      ctx[((size_t)(b * Ss + rrow[r2])) * Dd + h * HDd + n * 16 + ln] = (bf16)val;
    }
}

extern "C" void kernel_launch(void* const* d_in, const int* in_sizes, int n_in,
                              void* d_out, int out_size, void* d_ws, size_t ws_size,
                              hipStream_t stream) {
  const float* x = (const float*)d_in[0];
  const int* doc = (const int*)d_in[1];
  const float* Wq = (const float*)d_in[2];
  const float* Wk = (const float*)d_in[3];
  const float* Wv = (const float*)d_in[4];
  const float* Wo = (const float*)d_in[5];
  const float* bo = (const float*)d_in[6];
  float* outp = (float*)d_out;

  char* ws = (char*)d_ws;
  size_t off = 0;
  auto alloc = [&](size_t bytes) {
    char* p = ws + off;
    off += (bytes + 255) & ~(size_t)255;
    return p;
  };
  bf16* xb = (bf16*)alloc((size_t)BSs * Dd * 2);
  bf16* wqkvt = (bf16*)alloc((size_t)3 * Dd * Dd * 2);  // [6144][2048]
  bf16* wot = (bf16*)alloc((size_t)Dd * Dd * 2);
  bf16* qd = (bf16*)alloc((size_t)BSs * Dd * 2);
  bf16* kd = (bf16*)alloc((size_t)BSs * Dd * 2);
  bf16* vtd = (bf16*)alloc((size_t)BSs * Dd * 2);  // V stored transposed directly
  bf16* ctxd = (bf16*)alloc((size_t)BSs * Dd * 2);
  int* pos = (int*)alloc((size_t)BSs * 4);

  k_cvtx<<<(BSs * Dd) / 1024, 256, 0, stream>>>(x, xb);
  k_tw<<<dim3(Dd / 64, Dd / 64, 4), 256, 0, stream>>>(
      Wq, Wk, Wv, Wo, wqkvt, wqkvt + (size_t)Dd * Dd, wqkvt + (size_t)2 * Dd * Dd, wot);
  k_pos<<<Bb, 1024, 0, stream>>>(doc, pos);
  k_qkv256<<<dim3(768), 512, 0, stream>>>(xb, wqkvt, pos, qd, kd, vtd);
  k_attn<<<dim3(512), 512, 0, stream>>>(qd, kd, vtd, pos, ctxd);
  k_out256<<<dim3(256), 512, 0, stream>>>(ctxd, wot, bo, outp);
}

// Round 9
// 218.518 us; speedup vs baseline: 1.0351x; 1.0351x over previous
//
#include <hip/hip_runtime.h>
#include <hip/hip_bf16.h>

#define Dd 2048
#define Ss 2048
#define Bb 2
#define Hh 16
#define HDd 128
#define BSs (Bb*Ss)
#define NTIL 32  // 2048 / 64 K-tiles

typedef __bf16 bf16;
typedef __bf16 bf16x8 __attribute__((ext_vector_type(8)));
typedef __bf16 bf16x4 __attribute__((ext_vector_type(4)));
typedef float f32x4 __attribute__((ext_vector_type(4)));

__device__ __forceinline__ void gload_lds16(const void* g, void* l) {
  __builtin_amdgcn_global_load_lds((__attribute__((address_space(1))) void*)(g),
                                   (__attribute__((address_space(3))) void*)(l), 16, 0, 0);
}

template <int N>
__device__ __forceinline__ void waitv() {
  if constexpr (N == 0) asm volatile("s_waitcnt vmcnt(0)" ::: "memory");
  else if constexpr (N == 6) asm volatile("s_waitcnt vmcnt(6)" ::: "memory");
  // N < 0: no wait
}

// ------------- fused prep: x->bf16 (z==4) + W transpose (z<4), one dispatch -------------
// z<4: W [K][N] fp32 -> Wt [N][K] bf16, 64x64 tiles (Wq/Wk/Wv -> wqkvt slabs, Wo -> wot).
// z==4: x fp32 -> xb bf16, 1024 blocks x 256 thr x 32 floats.
// Independent memory-bound phases share HBM BW in one dispatch (were serial kernels).
__global__ void k_prep(const float* __restrict__ x, bf16* __restrict__ xb,
                       const float* __restrict__ Wq, const float* __restrict__ Wk,
                       const float* __restrict__ Wv, const float* __restrict__ Wo,
                       bf16* __restrict__ wqkvt, bf16* __restrict__ wot) {
  __shared__ float t[64][65];
  int zz = blockIdx.z;
  int tid = threadIdx.x;  // 256

  if (zz == 4) {
    // ---- x -> bf16 ----
    int id = blockIdx.y * 32 + blockIdx.x;          // 0..1023
    size_t base = (size_t)id * 8192 + tid * 4;
#pragma unroll
    for (int it = 0; it < 8; it++) {
      size_t i = base + (size_t)it * 1024;
      f32x4 v = *(const f32x4*)(x + i);
      bf16x4 o;
      o[0] = (bf16)v[0]; o[1] = (bf16)v[1]; o[2] = (bf16)v[2]; o[3] = (bf16)v[3];
      *(bf16x4*)(xb + i) = o;
    }
    return;
  }

  // ---- W transpose ----
  const float* W = (zz == 0) ? Wq : (zz == 1) ? Wk : (zz == 2) ? Wv : Wo;
  bf16* T = (zz < 3) ? (wqkvt + (size_t)zz * Dd * Dd) : wot;
  int n0 = blockIdx.x * 64, k0 = blockIdx.y * 64;
#pragma unroll
  for (int rr = 0; rr < 4; rr++) {
    int r = (tid >> 4) + rr * 16;
    f32x4 vv = *(const f32x4*)(W + (size_t)(k0 + r) * Dd + n0 + (tid & 15) * 4);
#pragma unroll
    for (int j = 0; j < 4; j++) t[r][(tid & 15) * 4 + j] = vv[j];
  }
  __syncthreads();
#pragma unroll
  for (int rr = 0; rr < 4; rr++) {
    int n = rr * 16 + (tid >> 4);
    int kb = (tid & 15) * 4;
    bf16x4 o;
#pragma unroll
    for (int j = 0; j < 4; j++) o[j] = (bf16)t[kb + j][n];
    *(bf16x4*)(T + (size_t)(n0 + n) * Dd + k0 + kb) = o;
  }
}

// ------------- doc position ids (prefix-max scan per batch) -------------
__global__ void k_pos(const int* __restrict__ doc, int* __restrict__ pos) {
  int b = blockIdx.x;
  __shared__ int bp[2][Ss];
  const int* db = doc + (size_t)b * Ss;
  for (int i = threadIdx.x; i < Ss; i += 1024) {
    int bd = (i == 0) || (db[i] != db[i - 1]);
    bp[0][i] = bd ? i : 0;
  }
  __syncthreads();
  int src = 0;
  for (int off = 1; off < Ss; off <<= 1) {
    for (int i = threadIdx.x; i < Ss; i += 1024) {
      int v = bp[src][i];
      if (i >= off) v = max(v, bp[src][i - off]);
      bp[1 - src][i] = v;
    }
    __syncthreads();
    src = 1 - src;
  }
  for (int i = threadIdx.x; i < Ss; i += 1024)
    pos[(size_t)b * Ss + i] = i - bp[src][i];
}

// ================= 128x256 BK=64 GEMM core, TRIPLE-buffered, 1 barrier/K-tile =================
// Round-6 proven core (108.9 us, MfmaUtil 40, conflicts 262K). Unchanged.
__device__ __forceinline__ void stage64(const char* gA, const char* gB,
                                        int m0, int n0, int t, int buf,
                                        char* AL, char* BL, int tid) {
  int ktb = t * 128;  // K-tile byte offset in a 4096 B row
#pragma unroll
  for (int p = 0; p < 2; p++) {
    int o = p * 8192 + tid * 16;
    int r = o >> 7, cb = o & 127;
    gload_lds16(gA + (size_t)(m0 + r) * 4096 + ktb + (cb ^ ((r & 7) << 4)),
                AL + buf * 16384 + o);
  }
#pragma unroll
  for (int p = 0; p < 4; p++) {
    int o = p * 8192 + tid * 16;
    int r = o >> 7, cb = o & 127;
    gload_lds16(gB + (size_t)(n0 + r) * 4096 + ktb + (cb ^ ((r & 7) << 4)),
                BL + buf * 32768 + o);
  }
}

template <bool STAGE, int WV>
__device__ __forceinline__ void do_tile64(const char* gA, const char* gB, int m0, int n0,
                                          int t, int bi, int b2, char* AL, char* BL, int tid,
                                          int wr, int wc, int ln, int g,
                                          f32x4 (&acc)[4][4]) {
  if (STAGE) stage64(gA, gB, m0, n0, t + 2, b2, AL, BL, tid);
  const char* tA = AL + bi * 16384;
  const char* tB = BL + bi * 32768;
#pragma unroll
  for (int kk = 0; kk < 2; kk++) {
    bf16x8 af[4], bf[4];
#pragma unroll
    for (int mq = 0; mq < 4; mq++) {
      int row = wr * 64 + mq * 16 + ln;
      af[mq] = *(const bf16x8*)(tA + row * 128 + ((kk * 64 + g * 16) ^ ((row & 7) << 4)));
    }
#pragma unroll
    for (int nq = 0; nq < 4; nq++) {
      int row = wc * 64 + nq * 16 + ln;
      bf[nq] = *(const bf16x8*)(tB + row * 128 + ((kk * 64 + g * 16) ^ ((row & 7) << 4)));
    }
    __builtin_amdgcn_s_setprio(1);
#pragma unroll
    for (int mq = 0; mq < 4; mq++)
#pragma unroll
      for (int nq = 0; nq < 4; nq++)
        acc[mq][nq] = __builtin_amdgcn_mfma_f32_16x16x32_bf16(af[mq], bf[nq], acc[mq][nq], 0, 0, 0);
    __builtin_amdgcn_s_setprio(0);
  }
  waitv<WV>();
  __builtin_amdgcn_s_barrier();
}

__device__ __forceinline__ void gemm64_core(const bf16* gA_, const bf16* gB_,
                                            int m0, int n0, char* AL, char* BL,
                                            f32x4 (&acc)[4][4]) {
  const char* gA = (const char*)gA_;
  const char* gB = (const char*)gB_;
  const int tid = threadIdx.x;
  const int l = tid & 63, w = tid >> 6;
  const int wr = w >> 2, wc = w & 3;
  const int g = l >> 4, ln = l & 15;
  f32x4 z = {0.f, 0.f, 0.f, 0.f};
#pragma unroll
  for (int i = 0; i < 4; i++)
#pragma unroll
    for (int n = 0; n < 4; n++) acc[i][n] = z;

  stage64(gA, gB, m0, n0, 0, 0, AL, BL, tid);
  stage64(gA, gB, m0, n0, 1, 1, AL, BL, tid);
  waitv<6>();
  __builtin_amdgcn_s_barrier();

  for (int tt = 0; tt < 10; tt++) {
    int t = tt * 3;
    do_tile64<true, 6>(gA, gB, m0, n0, t,     0, 2, AL, BL, tid, wr, wc, ln, g, acc);
    do_tile64<true, 6>(gA, gB, m0, n0, t + 1, 1, 0, AL, BL, tid, wr, wc, ln, g, acc);
    do_tile64<true, 6>(gA, gB, m0, n0, t + 2, 2, 1, AL, BL, tid, wr, wc, ln, g, acc);
  }
  do_tile64<false, 0>(gA, gB, m0, n0, 30, 0, 0, AL, BL, tid, wr, wc, ln, g, acc);
  do_tile64<false, -1>(gA, gB, m0, n0, 31, 1, 0, AL, BL, tid, wr, wc, ln, g, acc);
}

// ------------- fused QKV projection + RoPE epilogue (128x256 tiles, 768 blocks = 3 exact rounds) -------------
// XCD-partitioned swizzle: XCD x owns nt in {3x,3x+1,3x+2} (B-panels 1.6 MB, L2-resident)
// for ALL 32 mt, mt-major. Round-6 proven (FETCH 107 MB). Unchanged.
__global__ __launch_bounds__(512, 2) void k_qkv256(const bf16* __restrict__ xb,
                                                   const bf16* __restrict__ wqkvt,
                                                   const int* __restrict__ pos,
                                                   bf16* __restrict__ q,
                                                   bf16* __restrict__ k,
                                                   bf16* __restrict__ vt) {
  __shared__ char SLM[147456];  // GEMM: A 3x16K + B 3x32K; epilogue: 64x260 f32 view (65 KB)
  char* AL = SLM;
  char* BL = SLM + 49152;
  int bid = blockIdx.x;                    // 768 blocks
  int x = bid & 7, j = bid >> 3;           // x = XCD, j = 0..95
  int mt = j / 3, nt = x * 3 + (j % 3);    // per-XCD: 3 nt panels x all mt, mt-major
  int m0 = mt * 128, n0 = nt * 256;

  f32x4 acc[4][4];
  gemm64_core(xb, wqkvt, m0, n0, AL, BL, acc);

  const int tid = threadIdx.x;
  const int l = tid & 63, w = tid >> 6;
  const int wr = w >> 2, wc = w & 3, g = l >> 4, ln = l & 15;
  int z = n0 >> 11;                         // 0=Q 1=K 2=V (block-uniform)
  int n0l = n0 & 2047;
  int bix = m0 >> 11;
  int sl0 = m0 & 2047;                      // 128-row tile never crosses batch boundary

  if (z == 2) {
    // V: straight from acc, transposed layout [B][H][HD][S], 8 B stores
#pragma unroll
    for (int mq = 0; mq < 4; mq++) {
      int sl = sl0 + wr * 64 + mq * 16 + g * 4;
#pragma unroll
      for (int nq = 0; nq < 4; nq++) {
        int col = n0l + wc * 64 + nq * 16 + ln;
        int h = col >> 7, hd = col & 127;
        bf16x4 o;
#pragma unroll
        for (int r2 = 0; r2 < 4; r2++) o[r2] = (bf16)acc[mq][nq][r2];
        *(bf16x4*)(vt + (((size_t)(bix * Hh + h) * HDd + hd) * Ss + sl)) = o;
      }
    }
  } else {
    bf16* dst = (z == 0) ? q : k;
    float* T = (float*)SLM;                 // stride 260 floats, 64 rows per pass
    const float c1 = 0.14391156642398168f;  // ln(10000)/64
    int cg = (tid & 31) * 8;                // per-thread column base (8 consecutive cols)
    int hb = n0l + cg;
    int hh = hb >> 7, hd0 = hb & 127;       // constant per thread
    float fr[4];
#pragma unroll
    for (int pr = 0; pr < 4; pr++)
      fr[pr] = __expf(-(float)((hd0 >> 1) + pr) * c1);

#pragma unroll
    for (int pass = 0; pass < 2; pass++) {
      __syncthreads();
      // scatter 64 rows of acc into LDS (waves with wr==pass own these rows)
      if (wr == pass) {
#pragma unroll
        for (int mq = 0; mq < 4; mq++) {
#pragma unroll
          for (int nq = 0; nq < 4; nq++) {
            int c = wc * 64 + nq * 16 + ln;
            int rb = mq * 16 + g * 4;
#pragma unroll
            for (int r2 = 0; r2 < 4; r2++)
              T[(rb + r2) * 260 + c] = acc[mq][nq][r2];
          }
        }
      }
      __syncthreads();
      // gather rows: 8 consecutive hd per thread, RoPE pairs in-register, 16 B stores
#pragma unroll
      for (int j2 = 0; j2 < 4; j2++) {
        int r = j2 * 16 + (tid >> 5);
        int sg = m0 + pass * 64 + r;
        float p = (float)pos[sg];
        f32x4 v0 = *(const f32x4*)(T + r * 260 + cg);
        f32x4 v1 = *(const f32x4*)(T + r * 260 + cg + 4);
        float e0[4] = {v0[0], v0[2], v1[0], v1[2]};
        float e1[4] = {v0[1], v0[3], v1[1], v1[3]};
        int s = sg & 2047;
        bf16x8 o;
#pragma unroll
        for (int pr = 0; pr < 4; pr++) {
          float ang = p * fr[pr];
          float sn, cs;
          __sincosf(ang, &sn, &cs);
          o[2 * pr]     = (bf16)(e0[pr] * cs - e1[pr] * sn);
          o[2 * pr + 1] = (bf16)(e1[pr] * cs + e0[pr] * sn);
        }
        *(bf16x8*)(dst + (((size_t)(bix * Hh + hh) * Ss + s) * HDd + hd0)) = o;
      }
    }
  }
}

// ------------- final projection + bias (fp32 out), 128x256 tiles, 256 blocks = 1 exact round -------------
// XCD-partitioned: XCD x owns nt = x (one 0.5 MB wot panel, L2-resident) x all 32 mt.
__global__ __launch_bounds__(512, 2) void k_out256(const bf16* __restrict__ ctx,
                                                   const bf16* __restrict__ wot,
                                                   const float* __restrict__ bo,
                                                   float* __restrict__ outp) {
  __shared__ char AL[49152];
  __shared__ char BL[98304];
  int bid = blockIdx.x;                    // 256 blocks
  int x = bid & 7, j = bid >> 3;           // x = XCD, j = 0..31
  int mt = j, nt = x;
  int m0 = mt * 128, n0 = nt * 256;

  f32x4 acc[4][4];
  gemm64_core(ctx, wot, m0, n0, AL, BL, acc);

  const int l = threadIdx.x & 63, w = threadIdx.x >> 6;
  const int wr = w >> 2, wc = w & 3, g = l >> 4, ln = l & 15;
  float bov[4];
#pragma unroll
  for (int nq = 0; nq < 4; nq++)
    bov[nq] = bo[n0 + wc * 64 + nq * 16 + ln];
#pragma unroll
  for (int mq = 0; mq < 4; mq++)
#pragma unroll
    for (int r2 = 0; r2 < 4; r2++) {
      int row = m0 + wr * 64 + mq * 16 + g * 4 + r2;
#pragma unroll
      for (int nq = 0; nq < 4; nq++) {
        int col = n0 + wc * 64 + nq * 16 + ln;
        outp[(size_t)row * Dd + col] = acc[mq][nq][r2] + bov[nq];
      }
    }
}

// ------------- flash attention with doc+causal mask (round-6 proven config, unchanged) -------------
// 1D grid 1024, XCD-partitioned: XCD x owns 4 (b,h) pairs (K/V 4 MB -> L2-resident
// across that head's 32 q-blocks).
__global__ __launch_bounds__(256) void k_attn(const bf16* __restrict__ q,
                                              const bf16* __restrict__ k,
                                              const bf16* __restrict__ vt,
                                              const int* __restrict__ pos,
                                              bf16* __restrict__ ctx) {
  __shared__ bf16 Ks[64 * 128];    // K tile  [kv][hd]
  __shared__ bf16 Vts[128 * 64];   // Vt tile [hd][kv]
  __shared__ bf16 Pw[4][16 * 64];  // per-wave P [qrow][kv]
  int bid = blockIdx.x;            // 1024
  int xc = bid & 7, jj = bid >> 3; // jj = 0..127
  int bh = xc * 4 + (jj >> 5);     // 4 heads per XCD
  int qt = jj & 31;
  int b = bh >> 4, h = bh & 15;
  int q0 = qt * 64;
  const int tid = threadIdx.x, l = tid & 63, w = tid >> 6, g = l >> 4, ln = l & 15;
  const bf16* qb = q + (size_t)bh * Ss * HDd;
  const bf16* kb = k + (size_t)bh * Ss * HDd;
  const bf16* vb = vt + (size_t)bh * Ss * HDd;

  bf16x8 qf[4];
  int qr = q0 + w * 16 + ln;
#pragma unroll
  for (int ks = 0; ks < 4; ks++)
    qf[ks] = *(const bf16x8*)(qb + (size_t)qr * HDd + ks * 32 + 8 * g);

  int rrow[4], dstart[4];
  float m[4], lsum[4];
#pragma unroll
  for (int r2 = 0; r2 < 4; r2++) {
    rrow[r2] = q0 + w * 16 + 4 * g + r2;
    dstart[r2] = rrow[r2] - pos[(size_t)b * Ss + rrow[r2]];
    m[r2] = -1e30f;
    lsum[r2] = 0.f;
  }
  f32x4 oacc[8];
  f32x4 z = {0.f, 0.f, 0.f, 0.f};
#pragma unroll
  for (int n = 0; n < 8; n++) oacc[n] = z;

  int kt_start = (q0 - pos[(size_t)b * Ss + q0]) >> 6;
  const float iscale = 0.08838834764831845f;  // 1/sqrt(128)

  for (int kt = kt_start; kt <= qt; kt++) {
    int kv0 = kt * 64;
#pragma unroll
    for (int i2 = 0; i2 < 4; i2++) {
      int o = i2 * 4096 + w * 1024 + l * 16;
      int rk = o >> 8, cbk = o & 255;
      gload_lds16((const char*)kb + (size_t)(kv0 + rk) * 256 + cbk,
                  (char*)Ks + i2 * 4096 + w * 1024);
      int rv = o >> 7, cbv = o & 127;
      gload_lds16((const char*)vb + (size_t)rv * (Ss * 2) + (size_t)kv0 * 2 + cbv,
                  (char*)Vts + i2 * 4096 + w * 1024);
    }
    __syncthreads();

    f32x4 sc[4];
#pragma unroll
    for (int n = 0; n < 4; n++) {
      f32x4 a = z;
#pragma unroll
      for (int ks = 0; ks < 4; ks++) {
        bf16x8 bfrag = *(const bf16x8*)(Ks + (n * 16 + ln) * 128 + ks * 32 + 8 * g);
        a = __builtin_amdgcn_mfma_f32_16x16x32_bf16(qf[ks], bfrag, a, 0, 0, 0);
      }
      sc[n] = a;
    }

    float pmax[4] = {-1e30f, -1e30f, -1e30f, -1e30f};
    float pv[4][4];
#pragma unroll
    for (int n = 0; n < 4; n++) {
      int kvc = kv0 + n * 16 + ln;
#pragma unroll
      for (int r2 = 0; r2 < 4; r2++) {
        bool ok = (kvc <= rrow[r2]) && (kvc >= dstart[r2]);
        float sv = ok ? sc[n][r2] * iscale : -1e30f;
        pv[n][r2] = sv;
        pmax[r2] = fmaxf(pmax[r2], sv);
      }
    }
#pragma unroll
    for (int off = 1; off < 16; off <<= 1)
#pragma unroll
      for (int r2 = 0; r2 < 4; r2++)
        pmax[r2] = fmaxf(pmax[r2], __shfl_xor(pmax[r2], off, 64));

    float alpha[4];
#pragma unroll
    for (int r2 = 0; r2 < 4; r2++) {
      float mn = fmaxf(m[r2], pmax[r2]);
      alpha[r2] = __expf(m[r2] - mn);
      m[r2] = mn;
    }

    float rs[4] = {0.f, 0.f, 0.f, 0.f};
#pragma unroll
    for (int n = 0; n < 4; n++) {
      int kvc = kv0 + n * 16 + ln;
#pragma unroll
      for (int r2 = 0; r2 < 4; r2++) {
        bool ok = (kvc <= rrow[r2]) && (kvc >= dstart[r2]);
        float p = ok ? __expf(pv[n][r2] - m[r2]) : 0.f;
        rs[r2] += p;
        Pw[w][(4 * g + r2) * 64 + n * 16 + ln] = (bf16)p;
      }
    }
#pragma unroll
    for (int off = 1; off < 16; off <<= 1)
#pragma unroll
      for (int r2 = 0; r2 < 4; r2++) rs[r2] += __shfl_xor(rs[r2], off, 64);
#pragma unroll
    for (int r2 = 0; r2 < 4; r2++) lsum[r2] = lsum[r2] * alpha[r2] + rs[r2];
#pragma unroll
    for (int n = 0; n < 8; n++)
#pragma unroll
      for (int r2 = 0; r2 < 4; r2++) oacc[n][r2] *= alpha[r2];
    __syncthreads();

#pragma unroll
    for (int n = 0; n < 8; n++) {
#pragma unroll
      for (int ks = 0; ks < 2; ks++) {
        bf16x8 pa = *(const bf16x8*)(&Pw[w][ln * 64 + ks * 32 + 8 * g]);
        bf16x8 vfr = *(const bf16x8*)(Vts + (n * 16 + ln) * 64 + ks * 32 + 8 * g);
        oacc[n] = __builtin_amdgcn_mfma_f32_16x16x32_bf16(pa, vfr, oacc[n], 0, 0, 0);
      }
    }
    __syncthreads();
  }

#pragma unroll
  for (int n = 0; n < 8; n++)
#pragma unroll
    for (int r2 = 0; r2 < 4; r2++) {
      float val = oacc[n][r2] / lsum[r2];
      ctx[((size_t)(b * Ss + rrow[r2])) * Dd + h * HDd + n * 16 + ln] = (bf16)val;
    }
}

extern "C" void kernel_launch(void* const* d_in, const int* in_sizes, int n_in,
                              void* d_out, int out_size, void* d_ws, size_t ws_size,
                              hipStream_t stream) {
  const float* x = (const float*)d_in[0];
  const int* doc = (const int*)d_in[1];
  const float* Wq = (const float*)d_in[2];
  const float* Wk = (const float*)d_in[3];
  const float* Wv = (const float*)d_in[4];
  const float* Wo = (const float*)d_in[5];
  const float* bo = (const float*)d_in[6];
  float* outp = (float*)d_out;

  char* ws = (char*)d_ws;
  size_t off = 0;
  auto alloc = [&](size_t bytes) {
    char* p = ws + off;
    off += (bytes + 255) & ~(size_t)255;
    return p;
  };
  bf16* xb = (bf16*)alloc((size_t)BSs * Dd * 2);
  bf16* wqkvt = (bf16*)alloc((size_t)3 * Dd * Dd * 2);  // [6144][2048]
  bf16* wot = (bf16*)alloc((size_t)Dd * Dd * 2);
  bf16* qd = (bf16*)alloc((size_t)BSs * Dd * 2);
  bf16* kd = (bf16*)alloc((size_t)BSs * Dd * 2);
  bf16* vtd = (bf16*)alloc((size_t)BSs * Dd * 2);  // V stored transposed directly
  bf16* ctxd = (bf16*)alloc((size_t)BSs * Dd * 2);
  int* pos = (int*)alloc((size_t)BSs * 4);

  k_prep<<<dim3(Dd / 64, Dd / 64, 5), 256, 0, stream>>>(x, xb, Wq, Wk, Wv, Wo, wqkvt, wot);
  k_pos<<<Bb, 1024, 0, stream>>>(doc, pos);
  k_qkv256<<<dim3(768), 512, 0, stream>>>(xb, wqkvt, pos, qd, kd, vtd);
  k_attn<<<dim3(1024), 256, 0, stream>>>(qd, kd, vtd, pos, ctxd);
  k_out256<<<dim3(256), 512, 0, stream>>>(ctxd, wot, bo, outp);
}

// Round 10
// 216.349 us; speedup vs baseline: 1.0454x; 1.0100x over previous
//
#include <hip/hip_runtime.h>
#include <hip/hip_bf16.h>

#define Dd 2048
#define Ss 2048
#define Bb 2
#define Hh 16
#define HDd 128
#define BSs (Bb*Ss)
#define NTIL 32  // 2048 / 64 K-tiles

typedef __bf16 bf16;
typedef __bf16 bf16x8 __attribute__((ext_vector_type(8)));
typedef __bf16 bf16x4 __attribute__((ext_vector_type(4)));
typedef float f32x4 __attribute__((ext_vector_type(4)));

__device__ __forceinline__ void gload_lds16(const void* g, void* l) {
  __builtin_amdgcn_global_load_lds((__attribute__((address_space(1))) void*)(g),
                                   (__attribute__((address_space(3))) void*)(l), 16, 0, 0);
}

template <int N>
__device__ __forceinline__ void waitv() {
  if constexpr (N == 0) asm volatile("s_waitcnt vmcnt(0)" ::: "memory");
  else if constexpr (N == 6) asm volatile("s_waitcnt vmcnt(6)" ::: "memory");
  // N < 0: no wait
}

// ------------- fused prep: x->bf16 (z==4) + W transpose (z<4) + doc pos scan (z==5) -------------
// z<4: W [K][N] fp32 -> Wt [N][K] bf16, 64x64 tiles (Wq/Wk/Wv -> wqkvt slabs, Wo -> wot).
// z==4: x fp32 -> xb bf16, 1024 blocks x 256 thr x 32 floats.
// z==5: blocks (0..1, 0): per-batch prefix-max scan for doc position ids (256-thr,
//       ping-pong buffers make the strided Hillis-Steele order-safe). Others exit.
// All independent phases share the GPU in one dispatch (pos was a serial 2-CU kernel).
__global__ void k_prep(const float* __restrict__ x, bf16* __restrict__ xb,
                       const float* __restrict__ Wq, const float* __restrict__ Wk,
                       const float* __restrict__ Wv, const float* __restrict__ Wo,
                       bf16* __restrict__ wqkvt, bf16* __restrict__ wot,
                       const int* __restrict__ doc, int* __restrict__ pos) {
  __shared__ char smem[16640];  // max(float t[64][65] = 16640 B, int bp[2][2048] = 16384 B)
  int zz = blockIdx.z;
  int tid = threadIdx.x;  // 256

  if (zz == 4) {
    // ---- x -> bf16 ----
    int id = blockIdx.y * 32 + blockIdx.x;          // 0..1023
    size_t base = (size_t)id * 8192 + tid * 4;
#pragma unroll
    for (int it = 0; it < 8; it++) {
      size_t i = base + (size_t)it * 1024;
      f32x4 v = *(const f32x4*)(x + i);
      bf16x4 o;
      o[0] = (bf16)v[0]; o[1] = (bf16)v[1]; o[2] = (bf16)v[2]; o[3] = (bf16)v[3];
      *(bf16x4*)(xb + i) = o;
    }
    return;
  }

  if (zz == 5) {
    // ---- doc position ids ----
    if (blockIdx.x >= Bb || blockIdx.y != 0) return;
    int b = blockIdx.x;
    int* bp = (int*)smem;  // [2][Ss]
    const int* db = doc + (size_t)b * Ss;
    for (int i = tid; i < Ss; i += 256) {
      int bd = (i == 0) || (db[i] != db[i - 1]);
      bp[i] = bd ? i : 0;
    }
    __syncthreads();
    int src = 0;
    for (int off = 1; off < Ss; off <<= 1) {
      for (int i = tid; i < Ss; i += 256) {
        int v = bp[src * Ss + i];
        if (i >= off) v = max(v, bp[src * Ss + i - off]);
        bp[(1 - src) * Ss + i] = v;
      }
      __syncthreads();
      src = 1 - src;
    }
    for (int i = tid; i < Ss; i += 256)
      pos[(size_t)b * Ss + i] = i - bp[src * Ss + i];
    return;
  }

  // ---- W transpose ----
  float (*t)[65] = (float(*)[65])smem;
  const float* W = (zz == 0) ? Wq : (zz == 1) ? Wk : (zz == 2) ? Wv : Wo;
  bf16* T = (zz < 3) ? (wqkvt + (size_t)zz * Dd * Dd) : wot;
  int n0 = blockIdx.x * 64, k0 = blockIdx.y * 64;
#pragma unroll
  for (int rr = 0; rr < 4; rr++) {
    int r = (tid >> 4) + rr * 16;
    f32x4 vv = *(const f32x4*)(W + (size_t)(k0 + r) * Dd + n0 + (tid & 15) * 4);
#pragma unroll
    for (int j = 0; j < 4; j++) t[r][(tid & 15) * 4 + j] = vv[j];
  }
  __syncthreads();
#pragma unroll
  for (int rr = 0; rr < 4; rr++) {
    int n = rr * 16 + (tid >> 4);
    int kb = (tid & 15) * 4;
    bf16x4 o;
#pragma unroll
    for (int j = 0; j < 4; j++) o[j] = (bf16)t[kb + j][n];
    *(bf16x4*)(T + (size_t)(n0 + n) * Dd + k0 + kb) = o;
  }
}

// ================= 128x256 BK=64 GEMM core, TRIPLE-buffered, 1 barrier/K-tile =================
// Round-6 proven core (108.5 us, MfmaUtil 40, conflicts 262K). Unchanged.
__device__ __forceinline__ void stage64(const char* gA, const char* gB,
                                        int m0, int n0, int t, int buf,
                                        char* AL, char* BL, int tid) {
  int ktb = t * 128;  // K-tile byte offset in a 4096 B row
#pragma unroll
  for (int p = 0; p < 2; p++) {
    int o = p * 8192 + tid * 16;
    int r = o >> 7, cb = o & 127;
    gload_lds16(gA + (size_t)(m0 + r) * 4096 + ktb + (cb ^ ((r & 7) << 4)),
                AL + buf * 16384 + o);
  }
#pragma unroll
  for (int p = 0; p < 4; p++) {
    int o = p * 8192 + tid * 16;
    int r = o >> 7, cb = o & 127;
    gload_lds16(gB + (size_t)(n0 + r) * 4096 + ktb + (cb ^ ((r & 7) << 4)),
                BL + buf * 32768 + o);
  }
}

template <bool STAGE, int WV>
__device__ __forceinline__ void do_tile64(const char* gA, const char* gB, int m0, int n0,
                                          int t, int bi, int b2, char* AL, char* BL, int tid,
                                          int wr, int wc, int ln, int g,
                                          f32x4 (&acc)[4][4]) {
  if (STAGE) stage64(gA, gB, m0, n0, t + 2, b2, AL, BL, tid);
  const char* tA = AL + bi * 16384;
  const char* tB = BL + bi * 32768;
#pragma unroll
  for (int kk = 0; kk < 2; kk++) {
    bf16x8 af[4], bf[4];
#pragma unroll
    for (int mq = 0; mq < 4; mq++) {
      int row = wr * 64 + mq * 16 + ln;
      af[mq] = *(const bf16x8*)(tA + row * 128 + ((kk * 64 + g * 16) ^ ((row & 7) << 4)));
    }
#pragma unroll
    for (int nq = 0; nq < 4; nq++) {
      int row = wc * 64 + nq * 16 + ln;
      bf[nq] = *(const bf16x8*)(tB + row * 128 + ((kk * 64 + g * 16) ^ ((row & 7) << 4)));
    }
    __builtin_amdgcn_s_setprio(1);
#pragma unroll
    for (int mq = 0; mq < 4; mq++)
#pragma unroll
      for (int nq = 0; nq < 4; nq++)
        acc[mq][nq] = __builtin_amdgcn_mfma_f32_16x16x32_bf16(af[mq], bf[nq], acc[mq][nq], 0, 0, 0);
    __builtin_amdgcn_s_setprio(0);
  }
  waitv<WV>();
  __builtin_amdgcn_s_barrier();
}

__device__ __forceinline__ void gemm64_core(const bf16* gA_, const bf16* gB_,
                                            int m0, int n0, char* AL, char* BL,
                                            f32x4 (&acc)[4][4]) {
  const char* gA = (const char*)gA_;
  const char* gB = (const char*)gB_;
  const int tid = threadIdx.x;
  const int l = tid & 63, w = tid >> 6;
  const int wr = w >> 2, wc = w & 3;
  const int g = l >> 4, ln = l & 15;
  f32x4 z = {0.f, 0.f, 0.f, 0.f};
#pragma unroll
  for (int i = 0; i < 4; i++)
#pragma unroll
    for (int n = 0; n < 4; n++) acc[i][n] = z;

  stage64(gA, gB, m0, n0, 0, 0, AL, BL, tid);
  stage64(gA, gB, m0, n0, 1, 1, AL, BL, tid);
  waitv<6>();
  __builtin_amdgcn_s_barrier();

  for (int tt = 0; tt < 10; tt++) {
    int t = tt * 3;
    do_tile64<true, 6>(gA, gB, m0, n0, t,     0, 2, AL, BL, tid, wr, wc, ln, g, acc);
    do_tile64<true, 6>(gA, gB, m0, n0, t + 1, 1, 0, AL, BL, tid, wr, wc, ln, g, acc);
    do_tile64<true, 6>(gA, gB, m0, n0, t + 2, 2, 1, AL, BL, tid, wr, wc, ln, g, acc);
  }
  do_tile64<false, 0>(gA, gB, m0, n0, 30, 0, 0, AL, BL, tid, wr, wc, ln, g, acc);
  do_tile64<false, -1>(gA, gB, m0, n0, 31, 1, 0, AL, BL, tid, wr, wc, ln, g, acc);
}

// ------------- fused QKV projection + RoPE epilogue — PERSISTENT (256 blocks x 3 nt) -------------
// 256 blocks = 1 block/CU = ONE exact round. Block (x=XCD, mt) computes its mt row for
// the XCD's 3 nt panels sequentially: A panel read once per block (L2-hot across the 3
// GEMMs), B panels (1.6 MB/XCD) L2-resident. Removes the 2 inter-round drain boundaries
// of the previous 768-block launch. __syncthreads() guards SLM reuse between the
// epilogue's T reads and the next GEMM's staging writes.
__global__ __launch_bounds__(512, 2) void k_qkv256(const bf16* __restrict__ xb,
                                                   const bf16* __restrict__ wqkvt,
                                                   const int* __restrict__ pos,
                                                   bf16* __restrict__ q,
                                                   bf16* __restrict__ k,
                                                   bf16* __restrict__ vt) {
  __shared__ char SLM[147456];  // GEMM: A 3x16K + B 3x32K; epilogue: 64x260 f32 view (65 KB)
  char* AL = SLM;
  char* BL = SLM + 49152;
  int bid = blockIdx.x;                    // 256 blocks
  int x = bid & 7, mt = bid >> 3;          // x = XCD, mt = 0..31
  int m0 = mt * 128;

  const int tid = threadIdx.x;
  const int l = tid & 63, w = tid >> 6;
  const int wr = w >> 2, wc = w & 3, g = l >> 4, ln = l & 15;
  int bix = m0 >> 11;
  int sl0 = m0 & 2047;                      // 128-row tile never crosses batch boundary

#pragma unroll 1
  for (int ni = 0; ni < 3; ni++) {
    int nt = x * 3 + ni;
    int n0 = nt * 256;
    f32x4 acc[4][4];
    gemm64_core(xb, wqkvt, m0, n0, AL, BL, acc);

    int z = n0 >> 11;                       // 0=Q 1=K 2=V (uniform per GEMM iteration)
    int n0l = n0 & 2047;

    if (z == 2) {
      // V: straight from acc, transposed layout [B][H][HD][S], 8 B stores
#pragma unroll
      for (int mq = 0; mq < 4; mq++) {
        int sl = sl0 + wr * 64 + mq * 16 + g * 4;
#pragma unroll
        for (int nq = 0; nq < 4; nq++) {
          int col = n0l + wc * 64 + nq * 16 + ln;
          int h = col >> 7, hd = col & 127;
          bf16x4 o;
#pragma unroll
          for (int r2 = 0; r2 < 4; r2++) o[r2] = (bf16)acc[mq][nq][r2];
          *(bf16x4*)(vt + (((size_t)(bix * Hh + h) * HDd + hd) * Ss + sl)) = o;
        }
      }
    } else {
      bf16* dst = (z == 0) ? q : k;
      float* T = (float*)SLM;                 // stride 260 floats, 64 rows per pass
      const float c1 = 0.14391156642398168f;  // ln(10000)/64
      int cg = (tid & 31) * 8;                // per-thread column base (8 consecutive cols)
      int hb = n0l + cg;
      int hh = hb >> 7, hd0 = hb & 127;       // constant per thread
      float fr[4];
#pragma unroll
      for (int pr = 0; pr < 4; pr++)
        fr[pr] = __expf(-(float)((hd0 >> 1) + pr) * c1);

#pragma unroll
      for (int pass = 0; pass < 2; pass++) {
        __syncthreads();
        // scatter 64 rows of acc into LDS (waves with wr==pass own these rows)
        if (wr == pass) {
#pragma unroll
          for (int mq = 0; mq < 4; mq++) {
#pragma unroll
            for (int nq = 0; nq < 4; nq++) {
              int c = wc * 64 + nq * 16 + ln;
              int rb = mq * 16 + g * 4;
#pragma unroll
              for (int r2 = 0; r2 < 4; r2++)
                T[(rb + r2) * 260 + c] = acc[mq][nq][r2];
            }
          }
        }
        __syncthreads();
        // gather rows: 8 consecutive hd per thread, RoPE pairs in-register, 16 B stores
#pragma unroll
        for (int j2 = 0; j2 < 4; j2++) {
          int r = j2 * 16 + (tid >> 5);
          int sg = m0 + pass * 64 + r;
          float p = (float)pos[sg];
          f32x4 v0 = *(const f32x4*)(T + r * 260 + cg);
          f32x4 v1 = *(const f32x4*)(T + r * 260 + cg + 4);
          float e0[4] = {v0[0], v0[2], v1[0], v1[2]};
          float e1[4] = {v0[1], v0[3], v1[1], v1[3]};
          int s = sg & 2047;
          bf16x8 o;
#pragma unroll
          for (int pr = 0; pr < 4; pr++) {
            float ang = p * fr[pr];
            float sn, cs;
            __sincosf(ang, &sn, &cs);
            o[2 * pr]     = (bf16)(e0[pr] * cs - e1[pr] * sn);
            o[2 * pr + 1] = (bf16)(e1[pr] * cs + e0[pr] * sn);
          }
          *(bf16x8*)(dst + (((size_t)(bix * Hh + hh) * Ss + s) * HDd + hd0)) = o;
        }
      }
    }
    __syncthreads();  // SLM (T / AL / BL) safe to restage for next nt
  }
}

// ------------- final projection + bias (fp32 out), 128x256 tiles, 256 blocks = 1 exact round -------------
// XCD-partitioned: XCD x owns nt = x (one 0.5 MB wot panel, L2-resident) x all 32 mt.
__global__ __launch_bounds__(512, 2) void k_out256(const bf16* __restrict__ ctx,
                                                   const bf16* __restrict__ wot,
                                                   const float* __restrict__ bo,
                                                   float* __restrict__ outp) {
  __shared__ char AL[49152];
  __shared__ char BL[98304];
  int bid = blockIdx.x;                    // 256 blocks
  int x = bid & 7, j = bid >> 3;           // x = XCD, j = 0..31
  int mt = j, nt = x;
  int m0 = mt * 128, n0 = nt * 256;

  f32x4 acc[4][4];
  gemm64_core(ctx, wot, m0, n0, AL, BL, acc);

  const int l = threadIdx.x & 63, w = threadIdx.x >> 6;
  const int wr = w >> 2, wc = w & 3, g = l >> 4, ln = l & 15;
  float bov[4];
#pragma unroll
  for (int nq = 0; nq < 4; nq++)
    bov[nq] = bo[n0 + wc * 64 + nq * 16 + ln];
#pragma unroll
  for (int mq = 0; mq < 4; mq++)
#pragma unroll
    for (int r2 = 0; r2 < 4; r2++) {
      int row = m0 + wr * 64 + mq * 16 + g * 4 + r2;
#pragma unroll
      for (int nq = 0; nq < 4; nq++) {
        int col = n0 + wc * 64 + nq * 16 + ln;
        outp[(size_t)row * Dd + col] = acc[mq][nq][r2] + bov[nq];
      }
    }
}

// ------------- flash attention with doc+causal mask (round-6 core; snake qt remap) -------------
// 1D grid 1024, XCD-partitioned: XCD x owns 4 (b,h) pairs (K/V 4 MB -> L2-resident).
// Snake remap pairs long (high-qt) and short (low-qt) causal blocks in dispatch order
// so co-resident blocks on a CU have balanced work (tail smoothing).
__global__ __launch_bounds__(256) void k_attn(const bf16* __restrict__ q,
                                              const bf16* __restrict__ k,
                                              const bf16* __restrict__ vt,
                                              const int* __restrict__ pos,
                                              bf16* __restrict__ ctx) {
  __shared__ bf16 Ks[64 * 128];    // K tile  [kv][hd]
  __shared__ bf16 Vts[128 * 64];   // Vt tile [hd][kv]
  __shared__ bf16 Pw[4][16 * 64];  // per-wave P [qrow][kv]
  int bid = blockIdx.x;            // 1024
  int xc = bid & 7, jj = bid >> 3; // jj = 0..127
  int bh = xc * 4 + (jj >> 5);     // 4 heads per XCD
  int idx5 = jj & 31;
  int qt = (idx5 & 1) ? (31 - (idx5 >> 1)) : (idx5 >> 1);  // snake: pair long+short
  int b = bh >> 4, h = bh & 15;
  int q0 = qt * 64;
  const int tid = threadIdx.x, l = tid & 63, w = tid >> 6, g = l >> 4, ln = l & 15;
  const bf16* qb = q + (size_t)bh * Ss * HDd;
  const bf16* kb = k + (size_t)bh * Ss * HDd;
  const bf16* vb = vt + (size_t)bh * Ss * HDd;

  bf16x8 qf[4];
  int qr = q0 + w * 16 + ln;
#pragma unroll
  for (int ks = 0; ks < 4; ks++)
    qf[ks] = *(const bf16x8*)(qb + (size_t)qr * HDd + ks * 32 + 8 * g);

  int rrow[4], dstart[4];
  float m[4], lsum[4];
#pragma unroll
  for (int r2 = 0; r2 < 4; r2++) {
    rrow[r2] = q0 + w * 16 + 4 * g + r2;
    dstart[r2] = rrow[r2] - pos[(size_t)b * Ss + rrow[r2]];
    m[r2] = -1e30f;
    lsum[r2] = 0.f;
  }
  f32x4 oacc[8];
  f32x4 z = {0.f, 0.f, 0.f, 0.f};
#pragma unroll
  for (int n = 0; n < 8; n++) oacc[n] = z;

  int kt_start = (q0 - pos[(size_t)b * Ss + q0]) >> 6;
  const float iscale = 0.08838834764831845f;  // 1/sqrt(128)

  for (int kt = kt_start; kt <= qt; kt++) {
    int kv0 = kt * 64;
#pragma unroll
    for (int i2 = 0; i2 < 4; i2++) {
      int o = i2 * 4096 + w * 1024 + l * 16;
      int rk = o >> 8, cbk = o & 255;
      gload_lds16((const char*)kb + (size_t)(kv0 + rk) * 256 + cbk,
                  (char*)Ks + i2 * 4096 + w * 1024);
      int rv = o >> 7, cbv = o & 127;
      gload_lds16((const char*)vb + (size_t)rv * (Ss * 2) + (size_t)kv0 * 2 + cbv,
                  (char*)Vts + i2 * 4096 + w * 1024);
    }
    __syncthreads();

    f32x4 sc[4];
#pragma unroll
    for (int n = 0; n < 4; n++) {
      f32x4 a = z;
#pragma unroll
      for (int ks = 0; ks < 4; ks++) {
        bf16x8 bfrag = *(const bf16x8*)(Ks + (n * 16 + ln) * 128 + ks * 32 + 8 * g);
        a = __builtin_amdgcn_mfma_f32_16x16x32_bf16(qf[ks], bfrag, a, 0, 0, 0);
      }
      sc[n] = a;
    }

    float pmax[4] = {-1e30f, -1e30f, -1e30f, -1e30f};
    float pv[4][4];
#pragma unroll
    for (int n = 0; n < 4; n++) {
      int kvc = kv0 + n * 16 + ln;
#pragma unroll
      for (int r2 = 0; r2 < 4; r2++) {
        bool ok = (kvc <= rrow[r2]) && (kvc >= dstart[r2]);
        float sv = ok ? sc[n][r2] * iscale : -1e30f;
        pv[n][r2] = sv;
        pmax[r2] = fmaxf(pmax[r2], sv);
      }
    }
#pragma unroll
    for (int off = 1; off < 16; off <<= 1)
#pragma unroll
      for (int r2 = 0; r2 < 4; r2++)
        pmax[r2] = fmaxf(pmax[r2], __shfl_xor(pmax[r2], off, 64));

    float alpha[4];
#pragma unroll
    for (int r2 = 0; r2 < 4; r2++) {
      float mn = fmaxf(m[r2], pmax[r2]);
      alpha[r2] = __expf(m[r2] - mn);
      m[r2] = mn;
    }

    float rs[4] = {0.f, 0.f, 0.f, 0.f};
#pragma unroll
    for (int n = 0; n < 4; n++) {
      int kvc = kv0 + n * 16 + ln;
#pragma unroll
      for (int r2 = 0; r2 < 4; r2++) {
        bool ok = (kvc <= rrow[r2]) && (kvc >= dstart[r2]);
        float p = ok ? __expf(pv[n][r2] - m[r2]) : 0.f;
        rs[r2] += p;
        Pw[w][(4 * g + r2) * 64 + n * 16 + ln] = (bf16)p;
      }
    }
#pragma unroll
    for (int off = 1; off < 16; off <<= 1)
#pragma unroll
      for (int r2 = 0; r2 < 4; r2++) rs[r2] += __shfl_xor(rs[r2], off, 64);
#pragma unroll
    for (int r2 = 0; r2 < 4; r2++) lsum[r2] = lsum[r2] * alpha[r2] + rs[r2];
#pragma unroll
    for (int n = 0; n < 8; n++)
#pragma unroll
      for (int r2 = 0; r2 < 4; r2++) oacc[n][r2] *= alpha[r2];
    __syncthreads();

#pragma unroll
    for (int n = 0; n < 8; n++) {
#pragma unroll
      for (int ks = 0; ks < 2; ks++) {
        bf16x8 pa = *(const bf16x8*)(&Pw[w][ln * 64 + ks * 32 + 8 * g]);
        bf16x8 vfr = *(const bf16x8*)(Vts + (n * 16 + ln) * 64 + ks * 32 + 8 * g);
        oacc[n] = __builtin_amdgcn_mfma_f32_16x16x32_bf16(pa, vfr, oacc[n], 0, 0, 0);
      }
    }
    __syncthreads();
  }

#pragma unroll
  for (int n = 0; n < 8; n++)
#pragma unroll
    for (int r2 = 0; r2 < 4; r2++) {
      float val = oacc[n][r2] / lsum[r2];
      ctx[((size_t)(b * Ss + rrow[r2])) * Dd + h * HDd + n * 16 + ln] = (bf16)val;
    }
}

extern "C" void kernel_launch(void* const* d_in, const int* in_sizes, int n_in,
                              void* d_out, int out_size, void* d_ws, size_t ws_size,
                              hipStream_t stream) {
  const float* x = (const float*)d_in[0];
  const int* doc = (const int*)d_in[1];
  const float* Wq = (const float*)d_in[2];
  const float* Wk = (const float*)d_in[3];
  const float* Wv = (const float*)d_in[4];
  const float* Wo = (const float*)d_in[5];
  const float* bo = (const float*)d_in[6];
  float* outp = (float*)d_out;

  char* ws = (char*)d_ws;
  size_t off = 0;
  auto alloc = [&](size_t bytes) {
    char* p = ws + off;
    off += (bytes + 255) & ~(size_t)255;
    return p;
  };
  bf16* xb = (bf16*)alloc((size_t)BSs * Dd * 2);
  bf16* wqkvt = (bf16*)alloc((size_t)3 * Dd * Dd * 2);  // [6144][2048]
  bf16* wot = (bf16*)alloc((size_t)Dd * Dd * 2);
  bf16* qd = (bf16*)alloc((size_t)BSs * Dd * 2);
  bf16* kd = (bf16*)alloc((size_t)BSs * Dd * 2);
  bf16* vtd = (bf16*)alloc((size_t)BSs * Dd * 2);  // V stored transposed directly
  bf16* ctxd = (bf16*)alloc((size_t)BSs * Dd * 2);
  int* pos = (int*)alloc((size_t)BSs * 4);

  k_prep<<<dim3(32, 32, 6), 256, 0, stream>>>(x, xb, Wq, Wk, Wv, Wo, wqkvt, wot, doc, pos);
  k_qkv256<<<dim3(256), 512, 0, stream>>>(xb, wqkvt, pos, qd, kd, vtd);
  k_attn<<<dim3(1024), 256, 0, stream>>>(qd, kd, vtd, pos, ctxd);
  k_out256<<<dim3(256), 512, 0, stream>>>(ctxd, wot, bo, outp);
}

// Round 11
// 215.799 us; speedup vs baseline: 1.0481x; 1.0025x over previous
//
#include <hip/hip_runtime.h>
#include <hip/hip_bf16.h>

#define Dd 2048
#define Ss 2048
#define Bb 2
#define Hh 16
#define HDd 128
#define BSs (Bb*Ss)
#define NTIL 32  // 2048 / 64 K-tiles

typedef __bf16 bf16;
typedef __bf16 bf16x8 __attribute__((ext_vector_type(8)));
typedef __bf16 bf16x4 __attribute__((ext_vector_type(4)));
typedef float f32x4 __attribute__((ext_vector_type(4)));

__device__ __forceinline__ void gload_lds16(const void* g, void* l) {
  __builtin_amdgcn_global_load_lds((__attribute__((address_space(1))) void*)(g),
                                   (__attribute__((address_space(3))) void*)(l), 16, 0, 0);
}

template <int N>
__device__ __forceinline__ void waitv() {
  if constexpr (N == 0) asm volatile("s_waitcnt vmcnt(0)" ::: "memory");
  else if constexpr (N == 6) asm volatile("s_waitcnt vmcnt(6)" ::: "memory");
  // N < 0: no wait
}

// ------------- fused prep: x->bf16 (z==4) + W transpose (z<4) + doc pos scan (z==5) -------------
// z<4: W [K][N] fp32 -> Wt [N][K] bf16, 64x64 tiles (Wq/Wk/Wv -> wqkvt slabs, Wo -> wot).
// z==4: x fp32 -> xb bf16, 1024 blocks x 256 thr x 32 floats.
// z==5: blocks (0..1, 0): per-batch prefix-max scan for doc position ids (256-thr,
//       ping-pong buffers make the strided Hillis-Steele order-safe). Others exit.
__global__ void k_prep(const float* __restrict__ x, bf16* __restrict__ xb,
                       const float* __restrict__ Wq, const float* __restrict__ Wk,
                       const float* __restrict__ Wv, const float* __restrict__ Wo,
                       bf16* __restrict__ wqkvt, bf16* __restrict__ wot,
                       const int* __restrict__ doc, int* __restrict__ pos) {
  __shared__ char smem[16640];  // max(float t[64][65] = 16640 B, int bp[2][2048] = 16384 B)
  int zz = blockIdx.z;
  int tid = threadIdx.x;  // 256

  if (zz == 4) {
    // ---- x -> bf16 ----
    int id = blockIdx.y * 32 + blockIdx.x;          // 0..1023
    size_t base = (size_t)id * 8192 + tid * 4;
#pragma unroll
    for (int it = 0; it < 8; it++) {
      size_t i = base + (size_t)it * 1024;
      f32x4 v = *(const f32x4*)(x + i);
      bf16x4 o;
      o[0] = (bf16)v[0]; o[1] = (bf16)v[1]; o[2] = (bf16)v[2]; o[3] = (bf16)v[3];
      *(bf16x4*)(xb + i) = o;
    }
    return;
  }

  if (zz == 5) {
    // ---- doc position ids ----
    if (blockIdx.x >= Bb || blockIdx.y != 0) return;
    int b = blockIdx.x;
    int* bp = (int*)smem;  // [2][Ss]
    const int* db = doc + (size_t)b * Ss;
    for (int i = tid; i < Ss; i += 256) {
      int bd = (i == 0) || (db[i] != db[i - 1]);
      bp[i] = bd ? i : 0;
    }
    __syncthreads();
    int src = 0;
    for (int off = 1; off < Ss; off <<= 1) {
      for (int i = tid; i < Ss; i += 256) {
        int v = bp[src * Ss + i];
        if (i >= off) v = max(v, bp[src * Ss + i - off]);
        bp[(1 - src) * Ss + i] = v;
      }
      __syncthreads();
      src = 1 - src;
    }
    for (int i = tid; i < Ss; i += 256)
      pos[(size_t)b * Ss + i] = i - bp[src * Ss + i];
    return;
  }

  // ---- W transpose ----
  float (*t)[65] = (float(*)[65])smem;
  const float* W = (zz == 0) ? Wq : (zz == 1) ? Wk : (zz == 2) ? Wv : Wo;
  bf16* T = (zz < 3) ? (wqkvt + (size_t)zz * Dd * Dd) : wot;
  int n0 = blockIdx.x * 64, k0 = blockIdx.y * 64;
#pragma unroll
  for (int rr = 0; rr < 4; rr++) {
    int r = (tid >> 4) + rr * 16;
    f32x4 vv = *(const f32x4*)(W + (size_t)(k0 + r) * Dd + n0 + (tid & 15) * 4);
#pragma unroll
    for (int j = 0; j < 4; j++) t[r][(tid & 15) * 4 + j] = vv[j];
  }
  __syncthreads();
#pragma unroll
  for (int rr = 0; rr < 4; rr++) {
    int n = rr * 16 + (tid >> 4);
    int kb = (tid & 15) * 4;
    bf16x4 o;
#pragma unroll
    for (int j = 0; j < 4; j++) o[j] = (bf16)t[kb + j][n];
    *(bf16x4*)(T + (size_t)(n0 + n) * Dd + k0 + kb) = o;
  }
}

// ================= 128x256 BK=64 GEMM core, TRIPLE-buffered, 1 barrier/K-tile =================
// Round-6 proven core (108.5 us, MfmaUtil 40, conflicts 262K). Unchanged.
__device__ __forceinline__ void stage64(const char* gA, const char* gB,
                                        int m0, int n0, int t, int buf,
                                        char* AL, char* BL, int tid) {
  int ktb = t * 128;  // K-tile byte offset in a 4096 B row
#pragma unroll
  for (int p = 0; p < 2; p++) {
    int o = p * 8192 + tid * 16;
    int r = o >> 7, cb = o & 127;
    gload_lds16(gA + (size_t)(m0 + r) * 4096 + ktb + (cb ^ ((r & 7) << 4)),
                AL + buf * 16384 + o);
  }
#pragma unroll
  for (int p = 0; p < 4; p++) {
    int o = p * 8192 + tid * 16;
    int r = o >> 7, cb = o & 127;
    gload_lds16(gB + (size_t)(n0 + r) * 4096 + ktb + (cb ^ ((r & 7) << 4)),
                BL + buf * 32768 + o);
  }
}

template <bool STAGE, int WV>
__device__ __forceinline__ void do_tile64(const char* gA, const char* gB, int m0, int n0,
                                          int t, int bi, int b2, char* AL, char* BL, int tid,
                                          int wr, int wc, int ln, int g,
                                          f32x4 (&acc)[4][4]) {
  if (STAGE) stage64(gA, gB, m0, n0, t + 2, b2, AL, BL, tid);
  const char* tA = AL + bi * 16384;
  const char* tB = BL + bi * 32768;
#pragma unroll
  for (int kk = 0; kk < 2; kk++) {
    bf16x8 af[4], bf[4];
#pragma unroll
    for (int mq = 0; mq < 4; mq++) {
      int row = wr * 64 + mq * 16 + ln;
      af[mq] = *(const bf16x8*)(tA + row * 128 + ((kk * 64 + g * 16) ^ ((row & 7) << 4)));
    }
#pragma unroll
    for (int nq = 0; nq < 4; nq++) {
      int row = wc * 64 + nq * 16 + ln;
      bf[nq] = *(const bf16x8*)(tB + row * 128 + ((kk * 64 + g * 16) ^ ((row & 7) << 4)));
    }
    __builtin_amdgcn_s_setprio(1);
#pragma unroll
    for (int mq = 0; mq < 4; mq++)
#pragma unroll
      for (int nq = 0; nq < 4; nq++)
        acc[mq][nq] = __builtin_amdgcn_mfma_f32_16x16x32_bf16(af[mq], bf[nq], acc[mq][nq], 0, 0, 0);
    __builtin_amdgcn_s_setprio(0);
  }
  waitv<WV>();
  __builtin_amdgcn_s_barrier();
}

__device__ __forceinline__ void gemm64_core(const bf16* gA_, const bf16* gB_,
                                            int m0, int n0, char* AL, char* BL,
                                            f32x4 (&acc)[4][4]) {
  const char* gA = (const char*)gA_;
  const char* gB = (const char*)gB_;
  const int tid = threadIdx.x;
  const int l = tid & 63, w = tid >> 6;
  const int wr = w >> 2, wc = w & 3;
  const int g = l >> 4, ln = l & 15;
  f32x4 z = {0.f, 0.f, 0.f, 0.f};
#pragma unroll
  for (int i = 0; i < 4; i++)
#pragma unroll
    for (int n = 0; n < 4; n++) acc[i][n] = z;

  stage64(gA, gB, m0, n0, 0, 0, AL, BL, tid);
  stage64(gA, gB, m0, n0, 1, 1, AL, BL, tid);
  waitv<6>();
  __builtin_amdgcn_s_barrier();

  for (int tt = 0; tt < 10; tt++) {
    int t = tt * 3;
    do_tile64<true, 6>(gA, gB, m0, n0, t,     0, 2, AL, BL, tid, wr, wc, ln, g, acc);
    do_tile64<true, 6>(gA, gB, m0, n0, t + 1, 1, 0, AL, BL, tid, wr, wc, ln, g, acc);
    do_tile64<true, 6>(gA, gB, m0, n0, t + 2, 2, 1, AL, BL, tid, wr, wc, ln, g, acc);
  }
  do_tile64<false, 0>(gA, gB, m0, n0, 30, 0, 0, AL, BL, tid, wr, wc, ln, g, acc);
  do_tile64<false, -1>(gA, gB, m0, n0, 31, 1, 0, AL, BL, tid, wr, wc, ln, g, acc);
}

// ------------- fused QKV projection + RoPE epilogue (128x256 tiles, 768 blocks = 3 exact rounds) -------------
// REVERTED to round-9 proven version (108.5 us, FETCH 107 MB, VGPR 88): the round-10
// persistent 256-block variant doubled FETCH (A working set 16 MB/XCD > 4 MB L2 ->
// A re-fetched per nt). XCD-partitioned swizzle: XCD x owns nt in {3x,3x+1,3x+2}
// (B-panels 1.6 MB, L2-resident) for ALL 32 mt, mt-major (A panels shared by 3
// concurrent blocks per round).
__global__ __launch_bounds__(512, 2) void k_qkv256(const bf16* __restrict__ xb,
                                                   const bf16* __restrict__ wqkvt,
                                                   const int* __restrict__ pos,
                                                   bf16* __restrict__ q,
                                                   bf16* __restrict__ k,
                                                   bf16* __restrict__ vt) {
  __shared__ char SLM[147456];  // GEMM: A 3x16K + B 3x32K; epilogue: 64x260 f32 view (65 KB)
  char* AL = SLM;
  char* BL = SLM + 49152;
  int bid = blockIdx.x;                    // 768 blocks
  int x = bid & 7, j = bid >> 3;           // x = XCD, j = 0..95
  int mt = j / 3, nt = x * 3 + (j % 3);    // per-XCD: 3 nt panels x all mt, mt-major
  int m0 = mt * 128, n0 = nt * 256;

  f32x4 acc[4][4];
  gemm64_core(xb, wqkvt, m0, n0, AL, BL, acc);

  const int tid = threadIdx.x;
  const int l = tid & 63, w = tid >> 6;
  const int wr = w >> 2, wc = w & 3, g = l >> 4, ln = l & 15;
  int z = n0 >> 11;                         // 0=Q 1=K 2=V (block-uniform)
  int n0l = n0 & 2047;
  int bix = m0 >> 11;
  int sl0 = m0 & 2047;                      // 128-row tile never crosses batch boundary

  if (z == 2) {
    // V: straight from acc, transposed layout [B][H][HD][S], 8 B stores
#pragma unroll
    for (int mq = 0; mq < 4; mq++) {
      int sl = sl0 + wr * 64 + mq * 16 + g * 4;
#pragma unroll
      for (int nq = 0; nq < 4; nq++) {
        int col = n0l + wc * 64 + nq * 16 + ln;
        int h = col >> 7, hd = col & 127;
        bf16x4 o;
#pragma unroll
        for (int r2 = 0; r2 < 4; r2++) o[r2] = (bf16)acc[mq][nq][r2];
        *(bf16x4*)(vt + (((size_t)(bix * Hh + h) * HDd + hd) * Ss + sl)) = o;
      }
    }
  } else {
    bf16* dst = (z == 0) ? q : k;
    float* T = (float*)SLM;                 // stride 260 floats, 64 rows per pass
    const float c1 = 0.14391156642398168f;  // ln(10000)/64
    int cg = (tid & 31) * 8;                // per-thread column base (8 consecutive cols)
    int hb = n0l + cg;
    int hh = hb >> 7, hd0 = hb & 127;       // constant per thread
    float fr[4];
#pragma unroll
    for (int pr = 0; pr < 4; pr++)
      fr[pr] = __expf(-(float)((hd0 >> 1) + pr) * c1);

#pragma unroll
    for (int pass = 0; pass < 2; pass++) {
      __syncthreads();
      // scatter 64 rows of acc into LDS (waves with wr==pass own these rows)
      if (wr == pass) {
#pragma unroll
        for (int mq = 0; mq < 4; mq++) {
#pragma unroll
          for (int nq = 0; nq < 4; nq++) {
            int c = wc * 64 + nq * 16 + ln;
            int rb = mq * 16 + g * 4;
#pragma unroll
            for (int r2 = 0; r2 < 4; r2++)
              T[(rb + r2) * 260 + c] = acc[mq][nq][r2];
          }
        }
      }
      __syncthreads();
      // gather rows: 8 consecutive hd per thread, RoPE pairs in-register, 16 B stores
#pragma unroll
      for (int j2 = 0; j2 < 4; j2++) {
        int r = j2 * 16 + (tid >> 5);
        int sg = m0 + pass * 64 + r;
        float p = (float)pos[sg];
        f32x4 v0 = *(const f32x4*)(T + r * 260 + cg);
        f32x4 v1 = *(const f32x4*)(T + r * 260 + cg + 4);
        float e0[4] = {v0[0], v0[2], v1[0], v1[2]};
        float e1[4] = {v0[1], v0[3], v1[1], v1[3]};
        int s = sg & 2047;
        bf16x8 o;
#pragma unroll
        for (int pr = 0; pr < 4; pr++) {
          float ang = p * fr[pr];
          float sn, cs;
          __sincosf(ang, &sn, &cs);
          o[2 * pr]     = (bf16)(e0[pr] * cs - e1[pr] * sn);
          o[2 * pr + 1] = (bf16)(e1[pr] * cs + e0[pr] * sn);
        }
        *(bf16x8*)(dst + (((size_t)(bix * Hh + hh) * Ss + s) * HDd + hd0)) = o;
      }
    }
  }
}

// ------------- final projection + bias (fp32 out), 128x256 tiles, 256 blocks = 1 exact round -------------
// XCD-partitioned: XCD x owns nt = x (one 0.5 MB wot panel, L2-resident) x all 32 mt.
__global__ __launch_bounds__(512, 2) void k_out256(const bf16* __restrict__ ctx,
                                                   const bf16* __restrict__ wot,
                                                   const float* __restrict__ bo,
                                                   float* __restrict__ outp) {
  __shared__ char AL[49152];
  __shared__ char BL[98304];
  int bid = blockIdx.x;                    // 256 blocks
  int x = bid & 7, j = bid >> 3;           // x = XCD, j = 0..31
  int mt = j, nt = x;
  int m0 = mt * 128, n0 = nt * 256;

  f32x4 acc[4][4];
  gemm64_core(ctx, wot, m0, n0, AL, BL, acc);

  const int l = threadIdx.x & 63, w = threadIdx.x >> 6;
  const int wr = w >> 2, wc = w & 3, g = l >> 4, ln = l & 15;
  float bov[4];
#pragma unroll
  for (int nq = 0; nq < 4; nq++)
    bov[nq] = bo[n0 + wc * 64 + nq * 16 + ln];
#pragma unroll
  for (int mq = 0; mq < 4; mq++)
#pragma unroll
    for (int r2 = 0; r2 < 4; r2++) {
      int row = m0 + wr * 64 + mq * 16 + g * 4 + r2;
#pragma unroll
      for (int nq = 0; nq < 4; nq++) {
        int col = n0 + wc * 64 + nq * 16 + ln;
        outp[(size_t)row * Dd + col] = acc[mq][nq][r2] + bov[nq];
      }
    }
}

// ------------- flash attention with doc+causal mask (round-6 core; snake qt remap) -------------
// 1D grid 1024, XCD-partitioned: XCD x owns 4 (b,h) pairs (K/V 4 MB -> L2-resident).
// Snake remap pairs long (high-qt) and short (low-qt) causal blocks in dispatch order
// so co-resident blocks on a CU have balanced work (tail smoothing).
__global__ __launch_bounds__(256) void k_attn(const bf16* __restrict__ q,
                                              const bf16* __restrict__ k,
                                              const bf16* __restrict__ vt,
                                              const int* __restrict__ pos,
                                              bf16* __restrict__ ctx) {
  __shared__ bf16 Ks[64 * 128];    // K tile  [kv][hd]
  __shared__ bf16 Vts[128 * 64];   // Vt tile [hd][kv]
  __shared__ bf16 Pw[4][16 * 64];  // per-wave P [qrow][kv]
  int bid = blockIdx.x;            // 1024
  int xc = bid & 7, jj = bid >> 3; // jj = 0..127
  int bh = xc * 4 + (jj >> 5);     // 4 heads per XCD
  int idx5 = jj & 31;
  int qt = (idx5 & 1) ? (31 - (idx5 >> 1)) : (idx5 >> 1);  // snake: pair long+short
  int b = bh >> 4, h = bh & 15;
  int q0 = qt * 64;
  const int tid = threadIdx.x, l = tid & 63, w = tid >> 6, g = l >> 4, ln = l & 15;
  const bf16* qb = q + (size_t)bh * Ss * HDd;
  const bf16* kb = k + (size_t)bh * Ss * HDd;
  const bf16* vb = vt + (size_t)bh * Ss * HDd;

  bf16x8 qf[4];
  int qr = q0 + w * 16 + ln;
#pragma unroll
  for (int ks = 0; ks < 4; ks++)
    qf[ks] = *(const bf16x8*)(qb + (size_t)qr * HDd + ks * 32 + 8 * g);

  int rrow[4], dstart[4];
  float m[4], lsum[4];
#pragma unroll
  for (int r2 = 0; r2 < 4; r2++) {
    rrow[r2] = q0 + w * 16 + 4 * g + r2;
    dstart[r2] = rrow[r2] - pos[(size_t)b * Ss + rrow[r2]];
    m[r2] = -1e30f;
    lsum[r2] = 0.f;
  }
  f32x4 oacc[8];
  f32x4 z = {0.f, 0.f, 0.f, 0.f};
#pragma unroll
  for (int n = 0; n < 8; n++) oacc[n] = z;

  int kt_start = (q0 - pos[(size_t)b * Ss + q0]) >> 6;
  const float iscale = 0.08838834764831845f;  // 1/sqrt(128)

  for (int kt = kt_start; kt <= qt; kt++) {
    int kv0 = kt * 64;
#pragma unroll
    for (int i2 = 0; i2 < 4; i2++) {
      int o = i2 * 4096 + w * 1024 + l * 16;
      int rk = o >> 8, cbk = o & 255;
      gload_lds16((const char*)kb + (size_t)(kv0 + rk) * 256 + cbk,
                  (char*)Ks + i2 * 4096 + w * 1024);
      int rv = o >> 7, cbv = o & 127;
      gload_lds16((const char*)vb + (size_t)rv * (Ss * 2) + (size_t)kv0 * 2 + cbv,
                  (char*)Vts + i2 * 4096 + w * 1024);
    }
    __syncthreads();

    f32x4 sc[4];
#pragma unroll
    for (int n = 0; n < 4; n++) {
      f32x4 a = z;
#pragma unroll
      for (int ks = 0; ks < 4; ks++) {
        bf16x8 bfrag = *(const bf16x8*)(Ks + (n * 16 + ln) * 128 + ks * 32 + 8 * g);
        a = __builtin_amdgcn_mfma_f32_16x16x32_bf16(qf[ks], bfrag, a, 0, 0, 0);
      }
      sc[n] = a;
    }

    float pmax[4] = {-1e30f, -1e30f, -1e30f, -1e30f};
    float pv[4][4];
#pragma unroll
    for (int n = 0; n < 4; n++) {
      int kvc = kv0 + n * 16 + ln;
#pragma unroll
      for (int r2 = 0; r2 < 4; r2++) {
        bool ok = (kvc <= rrow[r2]) && (kvc >= dstart[r2]);
        float sv = ok ? sc[n][r2] * iscale : -1e30f;
        pv[n][r2] = sv;
        pmax[r2] = fmaxf(pmax[r2], sv);
      }
    }
#pragma unroll
    for (int off = 1; off < 16; off <<= 1)
#pragma unroll
      for (int r2 = 0; r2 < 4; r2++)
        pmax[r2] = fmaxf(pmax[r2], __shfl_xor(pmax[r2], off, 64));

    float alpha[4];
#pragma unroll
    for (int r2 = 0; r2 < 4; r2++) {
      float mn = fmaxf(m[r2], pmax[r2]);
      alpha[r2] = __expf(m[r2] - mn);
      m[r2] = mn;
    }

    float rs[4] = {0.f, 0.f, 0.f, 0.f};
#pragma unroll
    for (int n = 0; n < 4; n++) {
      int kvc = kv0 + n * 16 + ln;
#pragma unroll
      for (int r2 = 0; r2 < 4; r2++) {
        bool ok = (kvc <= rrow[r2]) && (kvc >= dstart[r2]);
        float p = ok ? __expf(pv[n][r2] - m[r2]) : 0.f;
        rs[r2] += p;
        Pw[w][(4 * g + r2) * 64 + n * 16 + ln] = (bf16)p;
      }
    }
#pragma unroll
    for (int off = 1; off < 16; off <<= 1)
#pragma unroll
      for (int r2 = 0; r2 < 4; r2++) rs[r2] += __shfl_xor(rs[r2], off, 64);
#pragma unroll
    for (int r2 = 0; r2 < 4; r2++) lsum[r2] = lsum[r2] * alpha[r2] + rs[r2];
#pragma unroll
    for (int n = 0; n < 8; n++)
#pragma unroll
      for (int r2 = 0; r2 < 4; r2++) oacc[n][r2] *= alpha[r2];
    __syncthreads();

#pragma unroll
    for (int n = 0; n < 8; n++) {
#pragma unroll
      for (int ks = 0; ks < 2; ks++) {
        bf16x8 pa = *(const bf16x8*)(&Pw[w][ln * 64 + ks * 32 + 8 * g]);
        bf16x8 vfr = *(const bf16x8*)(Vts + (n * 16 + ln) * 64 + ks * 32 + 8 * g);
        oacc[n] = __builtin_amdgcn_mfma_f32_16x16x32_bf16(pa, vfr, oacc[n], 0, 0, 0);
      }
    }
    __syncthreads();
  }

#pragma unroll
  for (int n = 0; n < 8; n++)
#pragma unroll
    for (int r2 = 0; r2 < 4; r2++) {
      float val = oacc[n][r2] / lsum[r2];
      ctx[((size_t)(b * Ss + rrow[r2])) * Dd + h * HDd + n * 16 + ln] = (bf16)val;
    }
}

extern "C" void kernel_launch(void* const* d_in, const int* in_sizes, int n_in,
                              void* d_out, int out_size, void* d_ws, size_t ws_size,
                              hipStream_t stream) {
  const float* x = (const float*)d_in[0];
  const int* doc = (const int*)d_in[1];
  const float* Wq = (const float*)d_in[2];
  const float* Wk = (const float*)d_in[3];
  const float* Wv = (const float*)d_in[4];
  const float* Wo = (const float*)d_in[5];
  const float* bo = (const float*)d_in[6];
  float* outp = (float*)d_out;

  char* ws = (char*)d_ws;
  size_t off = 0;
  auto alloc = [&](size_t bytes) {
    char* p = ws + off;
    off += (bytes + 255) & ~(size_t)255;
    return p;
  };
  bf16* xb = (bf16*)alloc((size_t)BSs * Dd * 2);
  bf16* wqkvt = (bf16*)alloc((size_t)3 * Dd * Dd * 2);  // [6144][2048]
  bf16* wot = (bf16*)alloc((size_t)Dd * Dd * 2);
  bf16* qd = (bf16*)alloc((size_t)BSs * Dd * 2);
  bf16* kd = (bf16*)alloc((size_t)BSs * Dd * 2);
  bf16* vtd = (bf16*)alloc((size_t)BSs * Dd * 2);  // V stored transposed directly
  bf16* ctxd = (bf16*)alloc((size_t)BSs * Dd * 2);
  int* pos = (int*)alloc((size_t)BSs * 4);

  k_prep<<<dim3(32, 32, 6), 256, 0, stream>>>(x, xb, Wq, Wk, Wv, Wo, wqkvt, wot, doc, pos);
  k_qkv256<<<dim3(768), 512, 0, stream>>>(xb, wqkvt, pos, qd, kd, vtd);
  k_attn<<<dim3(1024), 256, 0, stream>>>(qd, kd, vtd, pos, ctxd);
  k_out256<<<dim3(256), 512, 0, stream>>>(ctxd, wot, bo, outp);
}